// Round 1
// baseline (188.718 us; speedup 1.0000x reference)
//
#include <hip/hip_runtime.h>

// Problem constants (match reference)
constexpr int   Bsz = 32, Csz = 8, Hsz = 256, Wsz = 256;
constexpr int   HW  = Hsz * Wsz;            // 65536 pixels per plane
constexpr int   G   = Csz / 4;              // 2 groups
constexpr int   NBG = Bsz * G;              // 64 (b,g) slots
constexpr float THRESH      = 0.7f;
constexpr float MASK_WEIGHT = 0.7f;
constexpr float IM_WEIGHT   = 0.3f;

constexpr int BLK = 256;
constexpr int PIX4_PER_BG   = HW / 4;            // 16384 float4 groups per plane
constexpr int BLOCKS_PER_BG = PIX4_PER_BG / BLK; // 64 blocks per (b,g)

// ws float layout:
//   [0 .. G)                      : bce sum per group g  (sum of t*logp + (1-t)*log1mp)
//   [G .. G+NBG)                  : masked-norm sum per (b,g)
//   [G+NBG .. G+2*NBG)            : masked-nonzero count per (b,g)
//   [G+2*NBG .. G+3*NBG)          : diff_norm sum per (b,g)   (fallback mean)
constexpr int WS_FLOATS = G + 3 * NBG;           // 194

__global__ __launch_bounds__(256) void lp_zero(float* __restrict__ ws) {
    int i = threadIdx.x;
    if (i < WS_FLOATS) ws[i] = 0.0f;
}

__device__ __forceinline__ float get(const float4& v, int e) {
    return e == 0 ? v.x : e == 1 ? v.y : e == 2 ? v.z : v.w;
}

__global__ __launch_bounds__(256) void lp_mask_main(
    const float* __restrict__ out, const float* __restrict__ tar,
    float* __restrict__ ws)
{
    const int tid   = threadIdx.x;
    const int blk   = blockIdx.x;
    const int bg    = blk / BLOCKS_PER_BG;      // 0..63  (= b*G + g)
    const int chunk = blk % BLOCKS_PER_BG;
    const int g     = bg % G;

    // channel base: (b*C + g*4) * HW == bg * 4 * HW   (since C == 4*G)
    const size_t base = (size_t)bg * 4 * HW;
    const int    idx  = chunk * BLK + tid;      // float4 index within the plane

    const float4* po0 = reinterpret_cast<const float4*>(out + base);
    const float4* po1 = reinterpret_cast<const float4*>(out + base + HW);
    const float4* po2 = reinterpret_cast<const float4*>(out + base + 2 * (size_t)HW);
    const float4* po3 = reinterpret_cast<const float4*>(out + base + 3 * (size_t)HW);
    const float4* pt0 = reinterpret_cast<const float4*>(tar + base);
    const float4* pt1 = reinterpret_cast<const float4*>(tar + base + HW);
    const float4* pt2 = reinterpret_cast<const float4*>(tar + base + 2 * (size_t)HW);
    const float4* pt3 = reinterpret_cast<const float4*>(tar + base + 3 * (size_t)HW);

    const float4 a0 = po0[idx], a1 = po1[idx], a2 = po2[idx], a3 = po3[idx];
    const float4 b0 = pt0[idx], b1 = pt1[idx], b2 = pt2[idx], b3 = pt3[idx];

    float bce = 0.0f, msum = 0.0f, cnt = 0.0f, dsum = 0.0f;

#pragma unroll
    for (int e = 0; e < 4; ++e) {
        const float x  = get(a3, e);            // mask logit
        const float t  = get(b3, e);            // mask target
        const float d0 = get(a0, e) - get(b0, e);
        const float d1 = get(a1, e) - get(b1, e);
        const float d2 = get(a2, e) - get(b2, e);

        // mirror reference f32 sequence: p = sigmoid(x); clip(log p, -100); clip(log1p(-p), -100)
        const float p      = 1.0f / (1.0f + expf(-x));
        const float logp   = fmaxf(logf(p), -100.0f);
        const float log1mp = fmaxf(log1pf(-p), -100.0f);
        bce += t * logp + (1.0f - t) * log1mp;

        const float dn = sqrtf(d0 * d0 + d1 * d1 + d2 * d2);
        dsum += dn;
        if (p > THRESH) {
            msum += dn;
            cnt  += (dn != 0.0f) ? 1.0f : 0.0f;   // masked != 0 semantics
        }
    }

    // wave (64-lane) reduction
#pragma unroll
    for (int off = 32; off > 0; off >>= 1) {
        bce  += __shfl_down(bce,  off, 64);
        msum += __shfl_down(msum, off, 64);
        cnt  += __shfl_down(cnt,  off, 64);
        dsum += __shfl_down(dsum, off, 64);
    }

    __shared__ float s[4][4];                   // 4 waves x 4 quantities
    const int wave = tid >> 6, lane = tid & 63;
    if (lane == 0) {
        s[wave][0] = bce; s[wave][1] = msum; s[wave][2] = cnt; s[wave][3] = dsum;
    }
    __syncthreads();
    if (tid == 0) {
        float rb = 0.0f, rm = 0.0f, rc = 0.0f, rd = 0.0f;
#pragma unroll
        for (int w = 0; w < 4; ++w) {
            rb += s[w][0]; rm += s[w][1]; rc += s[w][2]; rd += s[w][3];
        }
        atomicAdd(&ws[g], rb);
        atomicAdd(&ws[G + bg], rm);
        atomicAdd(&ws[G + NBG + bg], rc);
        atomicAdd(&ws[G + 2 * NBG + bg], rd);
    }
}

__global__ __launch_bounds__(64) void lp_mask_final(
    const float* __restrict__ ws, float* __restrict__ outp)
{
    const int t = threadIdx.x;                  // one thread per (b,g), 64 total
    const float msum = ws[G + t];
    const float cnt  = ws[G + NBG + t];
    const float dsum = ws[G + 2 * NBG + t];

    float ps = (cnt > 0.0f) ? (msum / fmaxf(cnt, 1.0f)) : (dsum / (float)HW);

#pragma unroll
    for (int off = 32; off > 0; off >>= 1)
        ps += __shfl_down(ps, off, 64);

    if (t == 0) {
        float bce_total = 0.0f;
        for (int g = 0; g < G; ++g) bce_total += ws[g];
        // mean over g of mask_loss[g], mask_loss[g] = -bce_g / (B*HW)
        const float mask_mean = -bce_total / ((float)Bsz * (float)HW * (float)G);
        // mean over g of nocs_loss[g] = sum over (b,g) per_sample / (B*G)
        const float nocs_mean = ps / (float)(Bsz * G);
        outp[0] = MASK_WEIGHT * mask_mean + IM_WEIGHT * nocs_mean;
    }
}

extern "C" void kernel_launch(void* const* d_in, const int* in_sizes, int n_in,
                              void* d_out, int out_size, void* d_ws, size_t ws_size,
                              hipStream_t stream) {
    const float* out = (const float*)d_in[0];   // 'output' (logits etc.)
    const float* tar = (const float*)d_in[1];   // 'target'
    float* ws = (float*)d_ws;
    float* o  = (float*)d_out;

    lp_zero<<<1, 256, 0, stream>>>(ws);
    lp_mask_main<<<NBG * BLOCKS_PER_BG, BLK, 0, stream>>>(out, tar, ws);
    lp_mask_final<<<1, 64, 0, stream>>>(ws, o);
}

// Round 2
// 146.424 us; speedup vs baseline: 1.2888x; 1.2888x over previous
//
#include <hip/hip_runtime.h>

// Problem constants (match reference)
constexpr int   Bsz = 32, Csz = 8, Hsz = 256, Wsz = 256;
constexpr int   HW  = Hsz * Wsz;            // 65536 pixels per plane
constexpr int   G   = Csz / 4;              // 2 groups
constexpr int   NBG = Bsz * G;              // 64 (b,g) slots
constexpr float MASK_WEIGHT = 0.7f;
constexpr float IM_WEIGHT   = 0.3f;
// sigmoid(x) > 0.7  <=>  x > ln(0.7/0.3)
constexpr float XTHRESH = 0.8472978603872037f;

constexpr int BLK   = 256;
constexpr int ITERS = 2;                                  // float4 groups per thread per plane
constexpr int PIX4_PER_BG   = HW / 4;                     // 16384 float4 per plane
constexpr int BLOCKS_PER_BG = PIX4_PER_BG / (BLK * ITERS);// 32
constexpr int NB = NBG * BLOCKS_PER_BG;                   // 2048 blocks

// ws float layout (block-private slots -> no zero-init, no atomics):
//   pb[NB] : bce partial per block
//   pm[NB] : masked-norm sum partial
//   pc[NB] : masked count partial
//   pd[NB] : diff_norm sum partial (fallback)
//
__device__ __forceinline__ float get(const float4& v, int e) {
    return e == 0 ? v.x : e == 1 ? v.y : e == 2 ? v.z : v.w;
}

__global__ __launch_bounds__(256) void lp_mask_main(
    const float* __restrict__ out, const float* __restrict__ tar,
    float* __restrict__ ws)
{
    const int tid   = threadIdx.x;
    const int blk   = blockIdx.x;
    const int bg    = blk / BLOCKS_PER_BG;      // 0..63 (= b*G + g)
    const int chunk = blk % BLOCKS_PER_BG;

    // channel base: (b*C + g*4) * HW == bg * 4 * HW
    const size_t base = (size_t)bg * 4 * HW;
    const float4* po = reinterpret_cast<const float4*>(out + base);
    const float4* pt = reinterpret_cast<const float4*>(tar + base);
    constexpr int P4 = HW / 4;                  // float4 per plane

    float bce = 0.0f, msum = 0.0f, cnt = 0.0f, dsum = 0.0f;

    constexpr float LOG2E = 1.4426950408889634f;
    constexpr float LN2   = 0.6931471805599453f;

#pragma unroll
    for (int it = 0; it < ITERS; ++it) {
        const int idx = chunk * (BLK * ITERS) + it * BLK + tid;
        const float4 a0 = po[idx];
        const float4 a1 = po[idx + P4];
        const float4 a2 = po[idx + 2 * P4];
        const float4 a3 = po[idx + 3 * P4];
        const float4 b0 = pt[idx];
        const float4 b1 = pt[idx + P4];
        const float4 b2 = pt[idx + 2 * P4];
        const float4 b3 = pt[idx + 3 * P4];

#pragma unroll
        for (int e = 0; e < 4; ++e) {
            const float x  = get(a3, e);        // mask logit
            const float t  = get(b3, e);        // mask target
            const float d0 = get(a0, e) - get(b0, e);
            const float d1 = get(a1, e) - get(b1, e);
            const float d2 = get(a2, e) - get(b2, e);

            // t*log(sig(x)) + (1-t)*log(1-sig(x)) = t*x - softplus(x)
            // softplus(x) = max(x,0) + log1p(exp(-|x|)); clip(-100) dead for |x|<~90
            const float ax = __builtin_fabsf(x);
            const float ex = __builtin_exp2f(-ax * LOG2E);            // exp(-|x|)
            const float sp = fmaxf(x, 0.0f) + __builtin_log2f(1.0f + ex) * LN2;
            bce += __builtin_fmaf(t, x, -sp);

            const float dn = __builtin_sqrtf(d0 * d0 + d1 * d1 + d2 * d2);
            dsum += dn;
            if (x > XTHRESH) {
                msum += dn;
                cnt  += (dn != 0.0f) ? 1.0f : 0.0f;
            }
        }
    }

    // wave (64-lane) reduction
#pragma unroll
    for (int off = 32; off > 0; off >>= 1) {
        bce  += __shfl_down(bce,  off, 64);
        msum += __shfl_down(msum, off, 64);
        cnt  += __shfl_down(cnt,  off, 64);
        dsum += __shfl_down(dsum, off, 64);
    }

    __shared__ float s[4][4];                   // 4 waves x 4 quantities
    const int wave = tid >> 6, lane = tid & 63;
    if (lane == 0) {
        s[wave][0] = bce; s[wave][1] = msum; s[wave][2] = cnt; s[wave][3] = dsum;
    }
    __syncthreads();
    if (tid == 0) {
        float rb = 0.0f, rm = 0.0f, rc = 0.0f, rd = 0.0f;
#pragma unroll
        for (int w = 0; w < 4; ++w) {
            rb += s[w][0]; rm += s[w][1]; rc += s[w][2]; rd += s[w][3];
        }
        ws[blk]          = rb;                  // block-private: no atomics
        ws[NB + blk]     = rm;
        ws[2 * NB + blk] = rc;
        ws[3 * NB + blk] = rd;
    }
}

__global__ __launch_bounds__(64) void lp_mask_final(
    const float* __restrict__ ws, float* __restrict__ outp)
{
    const int t = threadIdx.x;                  // one thread per (b,g), 64 total

    float b = 0.0f, m = 0.0f, c = 0.0f, d = 0.0f;
    for (int i = 0; i < BLOCKS_PER_BG; ++i) {
        const int blk = t * BLOCKS_PER_BG + i;
        b += ws[blk];
        m += ws[NB + blk];
        c += ws[2 * NB + blk];
        d += ws[3 * NB + blk];
    }

    float ps = (c > 0.0f) ? (m / fmaxf(c, 1.0f)) : (d / (float)HW);

#pragma unroll
    for (int off = 32; off > 0; off >>= 1) {
        ps += __shfl_down(ps, off, 64);
        b  += __shfl_down(b,  off, 64);
    }

    if (t == 0) {
        // mean_g mask_loss = -bce_total / (G*B*HW); mean_g nocs = sum_ps / (B*G)
        const float mask_mean = -b / ((float)G * (float)Bsz * (float)HW);
        const float nocs_mean = ps / (float)(Bsz * G);
        outp[0] = MASK_WEIGHT * mask_mean + IM_WEIGHT * nocs_mean;
    }
}

extern "C" void kernel_launch(void* const* d_in, const int* in_sizes, int n_in,
                              void* d_out, int out_size, void* d_ws, size_t ws_size,
                              hipStream_t stream) {
    const float* out = (const float*)d_in[0];
    const float* tar = (const float*)d_in[1];
    float* ws = (float*)d_ws;
    float* o  = (float*)d_out;

    lp_mask_main<<<NB, BLK, 0, stream>>>(out, tar, ws);
    lp_mask_final<<<1, 64, 0, stream>>>(ws, o);
}